// Round 4
// baseline (210.057 us; speedup 1.0000x reference)
//
#include <hip/hip_runtime.h>

#define T_TOK 2048
#define DM    512
#define DFF   512
#define NE    16
#define LDK   72   // padded LDS row stride (ushorts): 144 B rotates banks by 4/row

typedef __attribute__((ext_vector_type(8))) short bf16x8;
typedef __attribute__((ext_vector_type(4))) float f32x4;
typedef __attribute__((ext_vector_type(8))) unsigned short us8;

__device__ __forceinline__ unsigned short f2bf(float f) {
  unsigned int u = __float_as_uint(f);
  u += 0x7fffu + ((u >> 16) & 1u);   // round-to-nearest-even
  return (unsigned short)(u >> 16);
}

// load 16 consecutive floats at p, convert to bf16
__device__ __forceinline__ void cvt16(const float* __restrict__ p, us8* o) {
  float4 v0 = *(const float4*)(p);
  float4 v1 = *(const float4*)(p + 4);
  float4 v2 = *(const float4*)(p + 8);
  float4 v3 = *(const float4*)(p + 12);
  us8 a, b;
  a[0]=f2bf(v0.x); a[1]=f2bf(v0.y); a[2]=f2bf(v0.z); a[3]=f2bf(v0.w);
  a[4]=f2bf(v1.x); a[5]=f2bf(v1.y); a[6]=f2bf(v1.z); a[7]=f2bf(v1.w);
  b[0]=f2bf(v2.x); b[1]=f2bf(v2.y); b[2]=f2bf(v2.z); b[3]=f2bf(v2.w);
  b[4]=f2bf(v3.x); b[5]=f2bf(v3.y); b[6]=f2bf(v3.z); b[7]=f2bf(v3.w);
  o[0]=a; o[1]=b;
}

// stage 16 elements: PRE = already-bf16 source (2 us8 loads), else fp32+convert
template<bool PRE>
__device__ __forceinline__ void stage16(const void* __restrict__ base, size_t off, us8* o) {
  if constexpr (PRE) {
    const unsigned short* p = (const unsigned short*)base + off;
    o[0] = *(const us8*)p;
    o[1] = *(const us8*)(p + 8);
  } else {
    cvt16((const float*)base + off, o);
  }
}

#define MFMA(a,b,c) __builtin_amdgcn_mfma_f32_16x16x32_bf16((a),(b),(c),0,0,0)

// ---------------- prep: blocks 0..511 router, 512+ fp32->bf16 convert ------
template<bool PRE>
__global__ __launch_bounds__(256) void prep_kernel(
    const float* __restrict__ x, const float* __restrict__ gw,
    const float* __restrict__ bias, int* __restrict__ counts,
    int* __restrict__ list, float* __restrict__ wgt,
    const float* __restrict__ sgu, const float* __restrict__ sdn,
    const float* __restrict__ egu, const float* __restrict__ edn,
    unsigned short* __restrict__ xb,   unsigned short* __restrict__ sgub,
    unsigned short* __restrict__ sdnb, unsigned short* __restrict__ egub,
    unsigned short* __restrict__ ednb)
{
  const int tid = threadIdx.x;
  if (blockIdx.x >= 512) {
    if constexpr (PRE) {
      // convert: group = 8 elems. x 131072 | sgu 65536 | sdn 32768 | egu 1048576 | edn 524288
      int g = (blockIdx.x - 512) * 256 + tid;
      const float* s; unsigned short* d; int l;
      if      (g <  131072) { s = x;   d = xb;   l = g;           }
      else if (g <  196608) { s = sgu; d = sgub; l = g -  131072; }
      else if (g <  229376) { s = sdn; d = sdnb; l = g -  196608; }
      else if (g < 1277952) { s = egu; d = egub; l = g -  229376; }
      else                  { s = edn; d = ednb; l = g - 1277952; }
      const float* p = s + (size_t)l * 8;
      float4 v0 = *(const float4*)p;
      float4 v1 = *(const float4*)(p + 4);
      us8 o;
      o[0]=f2bf(v0.x); o[1]=f2bf(v0.y); o[2]=f2bf(v0.z); o[3]=f2bf(v0.w);
      o[4]=f2bf(v1.x); o[5]=f2bf(v1.y); o[6]=f2bf(v1.z); o[7]=f2bf(v1.w);
      *(us8*)(d + (size_t)l * 8) = o;
    }
    return;
  }

  // ---- router: one token per wave ----
  __shared__ float lg[4][16];
  __shared__ int bcnt[16], bbase[16];
  __shared__ int sel_s[4][3], pos_s[4][3];
  __shared__ float g_s[4][3];

  const int w = tid >> 6, lane = tid & 63;
  if (tid < 16) bcnt[tid] = 0;
  const int tok = blockIdx.x * 4 + w;
  const int e = lane & 15, part = lane >> 4;

  const float* xr = x + (size_t)tok * DM + part * 128;
  const float* wr = gw + (size_t)e * DM + part * 128;
  float acc = 0.f;
  #pragma unroll 8
  for (int i = 0; i < 128; i += 4) {
    float4 xv = *(const float4*)(xr + i);
    float4 wv = *(const float4*)(wr + i);
    acc += xv.x*wv.x + xv.y*wv.y + xv.z*wv.z + xv.w*wv.w;
  }
  acc += __shfl_xor(acc, 16);
  acc += __shfl_xor(acc, 32);
  if (lane < 16) lg[w][lane] = 1.f / (1.f + __expf(-acc));  // affinity
  __syncthreads();

  if (tid < 4) {
    float aff[16], sc[16];
    #pragma unroll
    for (int i = 0; i < 16; ++i) { aff[i] = lg[tid][i]; sc[i] = aff[i] + bias[i]; }
    int sel[3]; float sa[3]; float sum = 0.f;
    #pragma unroll
    for (int k = 0; k < 3; ++k) {
      float best = -1e30f; int bi = 0;
      for (int i = 0; i < 16; ++i) {
        bool used = false;
        for (int j = 0; j < k; ++j) used |= (sel[j] == i);
        if (!used && sc[i] > best) { best = sc[i]; bi = i; }
      }
      sel[k] = bi; sa[k] = aff[bi]; sum += aff[bi];
    }
    float inv = 1.f / (sum + 1e-9f);
    #pragma unroll
    for (int k = 0; k < 3; ++k) {
      int p = atomicAdd(&bcnt[sel[k]], 1);
      sel_s[tid][k] = sel[k]; pos_s[tid][k] = p; g_s[tid][k] = sa[k] * inv;
    }
  }
  __syncthreads();
  if (tid < 16) bbase[tid] = atomicAdd(&counts[tid], bcnt[tid]);
  __syncthreads();
  if (tid < 4) {
    #pragma unroll
    for (int k = 0; k < 3; ++k) {
      int E = sel_s[tid][k];
      int p = bbase[E] + pos_s[tid][k];
      list[E * T_TOK + p] = blockIdx.x * 4 + tid;
      wgt [E * T_TOK + p] = g_s[tid][k];
    }
  }
}

// ---------------- GEMM1: 128 tok x 128 Hcols per block, wave 64x64 ---------
// z=0 shared expert, z>=1 routed expert z-1. Fused silu(g)*u -> Hall (bf16).
template<bool PRE>
__global__ __launch_bounds__(256, 2) void gemm1_fused(
    const void* __restrict__ X, const void* __restrict__ Wsh,
    const void* __restrict__ Wex, unsigned short* __restrict__ Hall,
    const int* __restrict__ counts, const int* __restrict__ list)
{
  __shared__ unsigned short As[128][LDK];
  __shared__ unsigned short Bs[256][LDK];   // rows 0-127: gate, 128-255: up

  const int n0 = blockIdx.x * 128;          // H col block
  const int mt = blockIdx.y, z = blockIdx.z;
  int cnt, hb; const void* W; size_t woff = 0;
  if (z == 0) { cnt = T_TOK; hb = 0; W = Wsh; }
  else {
    const int e = z - 1;
    cnt = counts[e];
    if (mt * 128 >= cnt) return;
    hb = T_TOK;
    for (int i = 0; i < e; ++i) hb += counts[i];
    W = Wex; woff = (size_t)e * (2 * DFF * DM);
  }

  const int tid = threadIdx.x;
  const int ar = tid >> 1, ac = (tid & 1) * 32;   // A staging: 32 elems/thread
  const int aent = mt * 128 + ar;
  const bool aval = aent < cnt;
  size_t aoff = 0;
  if (aval) {
    const int tok = (z == 0) ? aent : list[(z - 1) * T_TOK + aent];
    aoff = (size_t)tok * DM;
  }
  const int br = tid;                              // B staging: full 64-col row/thread
  const size_t boff = woff +
      (size_t)((br < 128) ? (n0 + br) : (DFF + n0 + (br - 128))) * DM;

  const int w  = tid >> 6;
  const int wm = (w & 1) * 64;       // wave row base
  const int wh = (w >> 1) * 64;      // wave H-col base
  const int lane = tid & 63, lr = lane & 15, qd = lane >> 4;

  const f32x4 z4 = {0.f, 0.f, 0.f, 0.f};
  f32x4 accg[4][4], accu[4][4];
  #pragma unroll
  for (int i = 0; i < 4; ++i)
    #pragma unroll
    for (int j = 0; j < 4; ++j) { accg[i][j] = z4; accu[i][j] = z4; }

  for (int k0 = 0; k0 < DM; k0 += 64) {
    us8 av[4] = {{0,0,0,0,0,0,0,0},{0,0,0,0,0,0,0,0},
                 {0,0,0,0,0,0,0,0},{0,0,0,0,0,0,0,0}};
    us8 bv[8];
    if (aval) {
      stage16<PRE>(X, aoff + k0 + ac,      av + 0);
      stage16<PRE>(X, aoff + k0 + ac + 16, av + 2);
    }
    stage16<PRE>(W, boff + k0,      bv + 0);
    stage16<PRE>(W, boff + k0 + 16, bv + 2);
    stage16<PRE>(W, boff + k0 + 32, bv + 4);
    stage16<PRE>(W, boff + k0 + 48, bv + 6);
    __syncthreads();
    *(us8*)&As[ar][ac]      = av[0];
    *(us8*)&As[ar][ac + 8]  = av[1];
    *(us8*)&As[ar][ac + 16] = av[2];
    *(us8*)&As[ar][ac + 24] = av[3];
    #pragma unroll
    for (int c = 0; c < 8; ++c) *(us8*)&Bs[br][c * 8] = bv[c];
    __syncthreads();
    #pragma unroll
    for (int ks = 0; ks < 2; ++ks) {
      const int kk = ks * 32 + qd * 8;
      bf16x8 a[4];
      #pragma unroll
      for (int i = 0; i < 4; ++i) a[i] = *(const bf16x8*)&As[wm + 16*i + lr][kk];
      #pragma unroll
      for (int j = 0; j < 4; ++j) {
        bf16x8 bg = *(const bf16x8*)&Bs[      wh + 16*j + lr][kk];
        bf16x8 bu = *(const bf16x8*)&Bs[128 + wh + 16*j + lr][kk];
        #pragma unroll
        for (int i = 0; i < 4; ++i) {
          accg[i][j] = MFMA(a[i], bg, accg[i][j]);
          accu[i][j] = MFMA(a[i], bu, accu[i][j]);
        }
      }
    }
  }

  #pragma unroll
  for (int i = 0; i < 4; ++i) {
    #pragma unroll
    for (int r = 0; r < 4; ++r) {
      const int ent = mt * 128 + wm + 16 * i + qd * 4 + r;
      if (ent < cnt) {
        const size_t rowoff = (size_t)(hb + ent) * DFF + n0 + wh;
        #pragma unroll
        for (int j = 0; j < 4; ++j) {
          float g = accg[i][j][r];
          float u = accu[i][j][r];
          float h = (g / (1.f + __expf(-g))) * u;   // silu(g)*u
          Hall[rowoff + 16 * j + lr] = f2bf(h);
        }
      }
    }
  }
}

// ---------------- GEMM2: 128 tok x 128 out-cols per block, wave 64x64 ------
template<bool PRE>
__global__ __launch_bounds__(256, 2) void gemm2_fused(
    const unsigned short* __restrict__ Hall, const void* __restrict__ Wsh,
    const void* __restrict__ Wex, float* __restrict__ out,
    const int* __restrict__ counts, const int* __restrict__ list,
    const float* __restrict__ wgt)
{
  __shared__ unsigned short Ah[128][LDK];
  __shared__ unsigned short Bd[128][LDK];

  const int n0 = blockIdx.x * 128;          // out col block
  const int mt = blockIdx.y, z = blockIdx.z;
  int cnt, hb; const void* W; size_t woff = 0;
  if (z == 0) { cnt = T_TOK; hb = 0; W = Wsh; }
  else {
    const int e = z - 1;
    cnt = counts[e];
    if (mt * 128 >= cnt) return;
    hb = T_TOK;
    for (int i = 0; i < e; ++i) hb += counts[i];
    W = Wex; woff = (size_t)e * (DM * DFF);
  }

  const int tid = threadIdx.x;
  const int ar = tid >> 1, ac = (tid & 1) * 32;   // 32 elems/thread
  const int aent = mt * 128 + ar;
  const bool aval = aent < cnt;
  const size_t aoff = aval ? (size_t)(hb + aent) * DFF : 0;
  const size_t boff = woff + (size_t)(n0 + ar) * DFF;

  const int w  = tid >> 6;
  const int wm = (w & 1) * 64;
  const int wn = (w >> 1) * 64;
  const int lane = tid & 63, lr = lane & 15, qd = lane >> 4;

  const f32x4 z4 = {0.f, 0.f, 0.f, 0.f};
  f32x4 acc[4][4];
  #pragma unroll
  for (int i = 0; i < 4; ++i)
    #pragma unroll
    for (int j = 0; j < 4; ++j) acc[i][j] = z4;

  for (int k0 = 0; k0 < DFF; k0 += 64) {
    us8 av[4] = {{0,0,0,0,0,0,0,0},{0,0,0,0,0,0,0,0},
                 {0,0,0,0,0,0,0,0},{0,0,0,0,0,0,0,0}};
    us8 bv[4];
    if (aval) {
      av[0] = *(const us8*)(Hall + aoff + k0 + ac);
      av[1] = *(const us8*)(Hall + aoff + k0 + ac + 8);
      av[2] = *(const us8*)(Hall + aoff + k0 + ac + 16);
      av[3] = *(const us8*)(Hall + aoff + k0 + ac + 24);
    }
    stage16<PRE>(W, boff + k0 + ac,      bv + 0);
    stage16<PRE>(W, boff + k0 + ac + 16, bv + 2);
    __syncthreads();
    *(us8*)&Ah[ar][ac]      = av[0];
    *(us8*)&Ah[ar][ac + 8]  = av[1];
    *(us8*)&Ah[ar][ac + 16] = av[2];
    *(us8*)&Ah[ar][ac + 24] = av[3];
    *(us8*)&Bd[ar][ac]      = bv[0];
    *(us8*)&Bd[ar][ac + 8]  = bv[1];
    *(us8*)&Bd[ar][ac + 16] = bv[2];
    *(us8*)&Bd[ar][ac + 24] = bv[3];
    __syncthreads();
    #pragma unroll
    for (int ks = 0; ks < 2; ++ks) {
      const int kk = ks * 32 + qd * 8;
      bf16x8 a[4];
      #pragma unroll
      for (int i = 0; i < 4; ++i) a[i] = *(const bf16x8*)&Ah[wm + 16*i + lr][kk];
      #pragma unroll
      for (int j = 0; j < 4; ++j) {
        bf16x8 b = *(const bf16x8*)&Bd[wn + 16*j + lr][kk];
        #pragma unroll
        for (int i = 0; i < 4; ++i) acc[i][j] = MFMA(a[i], b, acc[i][j]);
      }
    }
  }

  #pragma unroll
  for (int i = 0; i < 4; ++i) {
    #pragma unroll
    for (int r = 0; r < 4; ++r) {
      const int ent = mt * 128 + wm + 16 * i + qd * 4 + r;
      if (ent < cnt) {
        if (z == 0) {
          float* orow = out + (size_t)ent * DM + n0 + wn;
          #pragma unroll
          for (int j = 0; j < 4; ++j)
            atomicAdd(orow + 16 * j + lr, acc[i][j][r]);
        } else {
          const int   tok = list[(z - 1) * T_TOK + ent];
          const float g   = wgt [(z - 1) * T_TOK + ent];
          float* orow = out + (size_t)tok * DM + n0 + wn;
          #pragma unroll
          for (int j = 0; j < 4; ++j)
            atomicAdd(orow + 16 * j + lr, g * acc[i][j][r]);
        }
      }
    }
  }
}

// ---------------------------------------------------------------------------
extern "C" void kernel_launch(void* const* d_in, const int* in_sizes, int n_in,
                              void* d_out, int out_size, void* d_ws, size_t ws_size,
                              hipStream_t stream) {
  const float* x    = (const float*)d_in[0];
  const float* gw   = (const float*)d_in[1];
  const float* bias = (const float*)d_in[2];
  const float* sgu  = (const float*)d_in[3];
  const float* sdn  = (const float*)d_in[4];
  const float* egu  = (const float*)d_in[5];
  const float* edn  = (const float*)d_in[6];
  float* out = (float*)d_out;

  // workspace layout (bytes)
  char* ws = (char*)d_ws;
  int*            counts = (int*)(ws + 0);        // 16 ints
  int*            list   = (int*)(ws + 64);       // 16*2048 ints
  float*          wgt    = (float*)(ws + 131136); // 16*2048 floats
  unsigned short* Hall   = (unsigned short*)(ws + 262208); // 8192*512 bf16
  // preconverted bf16 copies (PRE path only)
  unsigned short* xb   = (unsigned short*)(ws + 8650816);
  unsigned short* sgub = (unsigned short*)(ws + 10747968);
  unsigned short* sdnb = (unsigned short*)(ws + 11796544);
  unsigned short* egub = (unsigned short*)(ws + 12320832);
  unsigned short* ednb = (unsigned short*)(ws + 29098048);
  const size_t need_base = 8650816, need_pre = 37486656;
  if (ws_size < need_base) return;
  const bool pre = ws_size >= need_pre;

  hipMemsetAsync(counts, 0, 64, stream);
  hipMemsetAsync(out, 0, (size_t)out_size * sizeof(float), stream);

  if (pre) {
    prep_kernel<true><<<512 + 7040, 256, 0, stream>>>(
        x, gw, bias, counts, list, wgt, sgu, sdn, egu, edn,
        xb, sgub, sdnb, egub, ednb);
    gemm1_fused<true ><<<dim3(4, 16, NE + 1), 256, 0, stream>>>(xb, sgub, egub, Hall, counts, list);
    gemm2_fused<true ><<<dim3(4, 16, NE + 1), 256, 0, stream>>>(Hall, sdnb, ednb, out, counts, list, wgt);
  } else {
    prep_kernel<false><<<512, 256, 0, stream>>>(
        x, gw, bias, counts, list, wgt, sgu, sdn, egu, edn,
        (unsigned short*)nullptr, (unsigned short*)nullptr,
        (unsigned short*)nullptr, (unsigned short*)nullptr,
        (unsigned short*)nullptr);
    gemm1_fused<false><<<dim3(4, 16, NE + 1), 256, 0, stream>>>(x, sgu, egu, Hall, counts, list);
    gemm2_fused<false><<<dim3(4, 16, NE + 1), 256, 0, stream>>>(Hall, sdn, edn, out, counts, list, wgt);
  }
}